// Round 7
// baseline (547.924 us; speedup 1.0000x reference)
//
#include <hip/hip_runtime.h>
#include <hip/hip_bf16.h>

typedef unsigned short u16;
typedef __attribute__((ext_vector_type(8))) short short8x;
typedef __attribute__((ext_vector_type(4))) unsigned short ushort4x;
typedef __attribute__((ext_vector_type(4))) float f32x4;

__device__ __forceinline__ float bf2f(u16 u){
    unsigned int v = ((unsigned int)u) << 16;
    return __builtin_bit_cast(float, v);
}
__device__ __forceinline__ u16 f2bf(float f){
    __hip_bfloat16 h = __float2bfloat16(f);
    return __builtin_bit_cast(unsigned short, h);
}
// load 8 contiguous fp32, convert to 8 bf16 (MFMA fragment)
__device__ __forceinline__ short8x cvt8(const float* __restrict__ p){
    const f32x4 a = *(const f32x4*)(p);
    const f32x4 b = *(const f32x4*)(p + 4);
    short8x r;
    #pragma unroll
    for (int e = 0; e < 4; ++e){ r[e] = (short)f2bf(a[e]); r[4 + e] = (short)f2bf(b[e]); }
    return r;
}

// One block = one 8x8 window. 256 threads = 4 waves. fp32 in / fp32 out.
// featT/outT/qT/vT are [token][channel]; knat and q1 are [channel][token].
// Row stride 72 bf16 = 144B: 16B-aligned rows, balanced b128 bank spans.
__global__ __launch_bounds__(256, 2)
void lwa_kernel(const float* __restrict__ x,
                const float* __restrict__ q_w, const float* __restrict__ q_bn,
                const float* __restrict__ k_w, const float* __restrict__ k_bn,
                const float* __restrict__ v_w, const float* __restrict__ v_bn,
                const float* __restrict__ dw_w, const float* __restrict__ dw_bn,
                const float* __restrict__ p_w, const float* __restrict__ p_bn,
                float* __restrict__ y)
{
    __shared__ u16 featT[64][72];   // current head input, [tok][ch]
    __shared__ u16 outT[64][72];    // attention output,  [tok][ch] (proj B operand)
    __shared__ u16 qT[64][72];      // q post dwconv+bn,  [tok][ch]
    __shared__ u16 knat[64][72];    // k,                 [ch][tok]
    __shared__ u16 vbuf[64][72];    // q1 [ch][tok] then vT [tok][ch]
    __shared__ float scq[64], shq[64], sck[64], shk[64], scv[64], shv[64], scdw[64], shdw[64];
    __shared__ float scp[256], shp[256];

    const int tid  = (int)threadIdx.x;
    const int lane = tid & 63;
    const int wid  = tid >> 6;
    const int g    = lane >> 4;   // 0..3
    const int r15  = lane & 15;

    // XCD swizzle: the 8 wx-sibling windows (sharing x cache lines) land on one XCD.
    const int hbid = (int)blockIdx.x;
    const int wndw = ((hbid & 511) << 3) | (hbid >> 9);
    const int bimg = wndw >> 6;
    const int wy   = (wndw >> 3) & 7;
    const int wx   = wndw & 7;
    const size_t x_img = (size_t)bimg * (256 * 4096);
    const int pix_base = wy * 8 * 64 + wx * 8;

    // fold projection BN
    {
        float gg = p_bn[tid];
        float bb = p_bn[256 + tid];
        float mm = p_bn[512 + tid];
        float vv = p_bn[768 + tid];
        float sc = gg * rsqrtf(vv + 1e-5f);
        scp[tid] = sc;
        shp[tid] = bb - mm * sc;
    }
    // load head-0 chunk into featT[tok][ch]
    {
        const int c = tid >> 2, qq = tid & 3;
        const float* xp = x + x_img + (size_t)c * 4096 + pix_base;
        #pragma unroll
        for (int rr = 0; rr < 2; ++rr){
            const int py = qq * 2 + rr;
            f32x4 r0 = *(const f32x4*)(xp + py * 64);
            f32x4 r1 = *(const f32x4*)(xp + py * 64 + 4);
            #pragma unroll
            for (int px = 0; px < 4; ++px){
                featT[py * 8 + px][c]     = f2bf(r0[px]);
                featT[py * 8 + 4 + px][c] = f2bf(r1[px]);
            }
        }
    }

    // projection accumulators: wave `wid` owns output rows [64*wid, 64*wid+64)
    f32x4 pacc[4][4];
    #pragma unroll
    for (int a = 0; a < 4; ++a)
        #pragma unroll
        for (int b = 0; b < 4; ++b)
            pacc[a][b] = (f32x4){0.f, 0.f, 0.f, 0.f};

    for (int i = 0; i < 4; ++i){
        __syncthreads();   // featT ready; previous head fully consumed
        // fold per-head BNs (one wave per bn set)
        {
            const int s = wid, ch = tid & 63;
            const float* bnb = (s == 0 ? q_bn : s == 1 ? k_bn : s == 2 ? v_bn : dw_bn) + i * 256;
            float gg = bnb[ch];
            float bb = bnb[64 + ch];
            float mm = bnb[128 + ch];
            float vv = bnb[192 + ch];
            float sc = gg * rsqrtf(vv + 1e-5f);
            float sh = bb - mm * sc;
            if (s == 0){ scq[ch] = sc; shq[ch] = sh; }
            else if (s == 1){ sck[ch] = sc; shk[ch] = sh; }
            else if (s == 2){ scv[ch] = sc; shv[ch] = sh; }
            else { scdw[ch] = sc; shdw[ch] = sh; }
        }
        __syncthreads();

        // ---- q = BN(q_w @ feat): MFMA -> vbuf as q1[ch][tok] ----
        {
            const float* Wg = q_w + i * 4096;
            const int arow = (wid * 16 + r15) * 64 + g * 8;
            const short8x a0 = cvt8(Wg + arow);
            const short8x a1 = cvt8(Wg + arow + 32);
            #pragma unroll
            for (int tc = 0; tc < 4; ++tc){
                f32x4 acc = (f32x4){0.f, 0.f, 0.f, 0.f};
                short8x b0 = *(const short8x*)(&featT[tc * 16 + r15][g * 8]);
                short8x b1 = *(const short8x*)(&featT[tc * 16 + r15][32 + g * 8]);
                acc = __builtin_amdgcn_mfma_f32_16x16x32_bf16(a0, b0, acc, 0, 0, 0);
                acc = __builtin_amdgcn_mfma_f32_16x16x32_bf16(a1, b1, acc, 0, 0, 0);
                #pragma unroll
                for (int r = 0; r < 4; ++r){
                    const int o = wid * 16 + g * 4 + r;
                    vbuf[o][tc * 16 + r15] = f2bf(acc[r] * scq[o] + shq[o]);
                }
            }
        }
        __syncthreads();

        // ---- depthwise 5x5 + BN -> qT[tok][ch]. thread: channel = tid&63, row pair = 2*wid ----
        {
            const int c = tid & 63, w2 = wid;
            float rin[6][8];
            #pragma unroll
            for (int rr = 0; rr < 6; ++rr){
                const int ry = 2 * w2 - 2 + rr;
                if (ry >= 0 && ry < 8){
                    short8x rv = *(const short8x*)(&vbuf[c][ry * 8]);
                    #pragma unroll
                    for (int e = 0; e < 8; ++e) rin[rr][e] = bf2f((u16)rv[e]);
                } else {
                    #pragma unroll
                    for (int e = 0; e < 8; ++e) rin[rr][e] = 0.f;
                }
            }
            float wt[25];
            const float* dwp = dw_w + (i * 64 + c) * 25;
            #pragma unroll
            for (int t5 = 0; t5 < 25; ++t5) wt[t5] = dwp[t5];
            const float sc = scdw[c], sh = shdw[c];
            #pragma unroll
            for (int oy = 0; oy < 2; ++oy){
                #pragma unroll
                for (int px = 0; px < 8; ++px){
                    float acc = 0.f;
                    #pragma unroll
                    for (int ky = 0; ky < 5; ++ky){
                        #pragma unroll
                        for (int kx = 0; kx < 5; ++kx){
                            const int ix = px - 2 + kx;            // compile-time bound check
                            if (ix >= 0 && ix < 8) acc += rin[oy + ky][ix] * wt[ky * 5 + kx];
                        }
                    }
                    qT[(2 * w2 + oy) * 8 + px][c] = f2bf(acc * sc + sh);
                }
            }
        }
        __syncthreads();   // q1 consumed; vbuf free for vT

        // ---- k -> knat[ch][tok]; v -> vbuf as vT[tok][ch] ----
        {
            const float* Wk = k_w + i * 4096;
            const int arow = (wid * 16 + r15) * 64 + g * 8;
            {
                const short8x a0 = cvt8(Wk + arow);
                const short8x a1 = cvt8(Wk + arow + 32);
                #pragma unroll
                for (int tc = 0; tc < 4; ++tc){
                    f32x4 acc = (f32x4){0.f, 0.f, 0.f, 0.f};
                    short8x b0 = *(const short8x*)(&featT[tc * 16 + r15][g * 8]);
                    short8x b1 = *(const short8x*)(&featT[tc * 16 + r15][32 + g * 8]);
                    acc = __builtin_amdgcn_mfma_f32_16x16x32_bf16(a0, b0, acc, 0, 0, 0);
                    acc = __builtin_amdgcn_mfma_f32_16x16x32_bf16(a1, b1, acc, 0, 0, 0);
                    #pragma unroll
                    for (int r = 0; r < 4; ++r){
                        const int o = wid * 16 + g * 4 + r;
                        knat[o][tc * 16 + r15] = f2bf(acc[r] * sck[o] + shk[o]);
                    }
                }
            }
            const float* Wv = v_w + i * 4096;
            {
                const short8x a0 = cvt8(Wv + arow);
                const short8x a1 = cvt8(Wv + arow + 32);
                #pragma unroll
                for (int tc = 0; tc < 4; ++tc){
                    f32x4 acc = (f32x4){0.f, 0.f, 0.f, 0.f};
                    short8x b0 = *(const short8x*)(&featT[tc * 16 + r15][g * 8]);
                    short8x b1 = *(const short8x*)(&featT[tc * 16 + r15][32 + g * 8]);
                    acc = __builtin_amdgcn_mfma_f32_16x16x32_bf16(a0, b0, acc, 0, 0, 0);
                    acc = __builtin_amdgcn_mfma_f32_16x16x32_bf16(a1, b1, acc, 0, 0, 0);
                    const int n2 = tc * 16 + r15, o0 = wid * 16 + g * 4;
                    ushort4x pk;
                    #pragma unroll
                    for (int r = 0; r < 4; ++r) pk[r] = f2bf(acc[r] * scv[o0 + r] + shv[o0 + r]);
                    *(ushort4x*)(&vbuf[n2][o0]) = pk;    // transposed, packed 8B
                }
            }
        }
        __syncthreads();

        // ---- attention: thread owns token n = tid>>2, channel quarter j = tid&3 ----
        // s[n][c] = qT[n][c] * knat[n][c]; softmax over c; outT[n][c] = vT[n][c]*a[c]
        {
            const int n = tid >> 2, j = tid & 3, c0 = j * 16;
            short8x qa0 = *(const short8x*)(&qT[n][c0]);
            short8x qa1 = *(const short8x*)(&qT[n][c0 + 8]);
            short8x ka0 = *(const short8x*)(&knat[n][c0]);
            short8x ka1 = *(const short8x*)(&knat[n][c0 + 8]);
            short8x va0 = *(const short8x*)(&vbuf[n][c0]);
            short8x va1 = *(const short8x*)(&vbuf[n][c0 + 8]);
            float s[16];
            #pragma unroll
            for (int e = 0; e < 8; ++e){
                s[e]     = bf2f((u16)qa0[e]) * bf2f((u16)ka0[e]);
                s[8 + e] = bf2f((u16)qa1[e]) * bf2f((u16)ka1[e]);
            }
            float m = s[0];
            #pragma unroll
            for (int e = 1; e < 16; ++e) m = fmaxf(m, s[e]);
            m = fmaxf(m, __shfl_xor(m, 1));
            m = fmaxf(m, __shfl_xor(m, 2));
            float sum = 0.f;
            #pragma unroll
            for (int e = 0; e < 16; ++e){ s[e] = __expf(s[e] - m); sum += s[e]; }
            sum += __shfl_xor(sum, 1);
            sum += __shfl_xor(sum, 2);
            const float inv = 1.f / sum;
            float ov[16];
            #pragma unroll
            for (int e = 0; e < 8; ++e){
                ov[e]     = bf2f((u16)va0[e]) * s[e] * inv;
                ov[8 + e] = bf2f((u16)va1[e]) * s[8 + e] * inv;
            }
            short8x o0v, o1v;
            #pragma unroll
            for (int e = 0; e < 8; ++e){ o0v[e] = (short)f2bf(ov[e]); o1v[e] = (short)f2bf(ov[8 + e]); }
            *(short8x*)(&outT[n][c0])     = o0v;
            *(short8x*)(&outT[n][c0 + 8]) = o1v;
            if (i < 3){
                // next head's feat = next chunk + out
                const int py = n >> 3, px = n & 7;
                const float* xc = x + x_img + pix_base + py * 64 + px + (size_t)((i + 1) * 64 + c0) * 4096;
                short8x f0v, f1v;
                #pragma unroll
                for (int e = 0; e < 8; ++e){
                    f0v[e] = (short)f2bf(xc[(size_t)e * 4096]       + ov[e]);
                    f1v[e] = (short)f2bf(xc[(size_t)(e + 8) * 4096] + ov[8 + e]);
                }
                *(short8x*)(&featT[n][c0])     = f0v;
                *(short8x*)(&featT[n][c0 + 8]) = f1v;
            }
        }
        __syncthreads();

        // ---- incremental projection: pacc += p_w[:, 64i:64i+64] @ outT^T ----
        {
            #pragma unroll
            for (int rt = 0; rt < 4; ++rt){
                #pragma unroll
                for (int kk = 0; kk < 2; ++kk){
                    const short8x a = cvt8(p_w + (size_t)(wid * 64 + rt * 16 + r15) * 256
                                           + i * 64 + kk * 32 + g * 8);
                    #pragma unroll
                    for (int tc = 0; tc < 4; ++tc){
                        short8x b = *(const short8x*)(&outT[tc * 16 + r15][kk * 32 + g * 8]);
                        pacc[rt][tc] = __builtin_amdgcn_mfma_f32_16x16x32_bf16(a, b, pacc[rt][tc], 0, 0, 0);
                    }
                }
            }
        }
    }

    // ---- epilogue: projection BN + window-reverse fp32 store ----
    #pragma unroll
    for (int rt = 0; rt < 4; ++rt){
        #pragma unroll
        for (int tc = 0; tc < 4; ++tc){
            #pragma unroll
            for (int r = 0; r < 4; ++r){
                const int o = wid * 64 + rt * 16 + g * 4 + r;
                const int n = tc * 16 + r15;
                const int py = n >> 3, px = n & 7;
                const float val = pacc[rt][tc][r] * scp[o] + shp[o];
                y[x_img + (size_t)o * 4096 + pix_base + py * 64 + px] = val;
            }
        }
    }
}

extern "C" void kernel_launch(void* const* d_in, const int* in_sizes, int n_in,
                              void* d_out, int out_size, void* d_ws, size_t ws_size,
                              hipStream_t stream) {
    const float* x    = (const float*)d_in[0];
    const float* q_w  = (const float*)d_in[1];
    const float* q_bn = (const float*)d_in[2];
    const float* k_w  = (const float*)d_in[3];
    const float* k_bn = (const float*)d_in[4];
    const float* v_w  = (const float*)d_in[5];
    const float* v_bn = (const float*)d_in[6];
    const float* dw_w = (const float*)d_in[7];
    const float* dw_bn= (const float*)d_in[8];
    const float* p_w  = (const float*)d_in[9];
    const float* p_bn = (const float*)d_in[10];
    float* yout = (float*)d_out;
    lwa_kernel<<<dim3(4096), dim3(256), 0, stream>>>(x, q_w, q_bn, k_w, k_bn, v_w, v_bn,
                                                     dw_w, dw_bn, p_w, p_bn, yout);
}